// Round 1
// baseline (107.099 us; speedup 1.0000x reference)
//
#include <hip/hip_runtime.h>
#include <math.h>

// SpectralAngleLoss: B=8192 rows, N=256 peaks, 2000 bins.
//
// Identity: with p[b] the final histogram, dot = sum_i pin_i*q[pbin_i],
// p2 = sum_i pin_i*p[pbin_i], t2 = sum_j tin_j*q[tbin_j] -> scalar LDS
// reads per peak after the scatter; no 2000-bin scan.
//
// v2: ONE wave per block, ONE 8 KB histogram, TWO PHASES per row
// (target scatter/gather/undo, then pred scatter/gather/undo). All DS ops
// are wave-ordered (single wave + in-order DS pipe) -> zero __syncthreads,
// fully deterministic, bit-identical math to the verified v1.
// 8000 B LDS/block -> 16 single-wave workgroups/CU (SPI cap) = 16 waves/CU,
// double v1's 8 waves/CU. Grid 4096 = exactly 16 x 256 CUs, all resident.

#define SAL_NUM_BINS 2000
#define SAL_B 8192
#define SAL_N 256
#define SAL_R 2                        // rows per block (per wave)
#define SAL_GRID (SAL_B / SAL_R)       // 4096 blocks -> 4096 partials

__global__ __launch_bounds__(64, 4) void sal_row_kernel(
    const float* __restrict__ pred_mz,
    const float* __restrict__ pred_int,
    const float* __restrict__ targ_mz,
    const float* __restrict__ targ_int,
    const float* __restrict__ targ_mask,
    float* __restrict__ block_partial)     // 4096 entries: sum of 2 angles
{
    __shared__ __align__(16) float hist[SAL_NUM_BINS];   // 8000 B, wave-private
    const int l = threadIdx.x;             // 0..63 (one wave per block)

    // issue all global loads for both rows first (10 x 16B/lane, coalesced)
    float4 pmz[SAL_R], pin[SAL_R], tmz[SAL_R], ti4[SAL_R], tm4[SAL_R];
    #pragma unroll
    for (int r = 0; r < SAL_R; ++r) {
        const int base = (blockIdx.x * SAL_R + r) * SAL_N;
        pmz[r] = ((const float4*)(pred_mz   + base))[l];
        pin[r] = ((const float4*)(pred_int  + base))[l];
        tmz[r] = ((const float4*)(targ_mz   + base))[l];
        ti4[r] = ((const float4*)(targ_int  + base))[l];
        tm4[r] = ((const float4*)(targ_mask + base))[l];
    }

    // zero the 8 KB histogram while the loads are in flight (no data dep).
    // Single wave -> DS in-order guarantees completion before the atomics.
    {
        float4* h4 = (float4*)hist;
        const float4 z = make_float4(0.f, 0.f, 0.f, 0.f);
        #pragma unroll
        for (int i = 0; i < 8; ++i) {
            const int idx = l + i * 64;
            if (idx < SAL_NUM_BINS / 4) h4[idx] = z;
        }
    }

    float dotv[SAL_R], p2v[SAL_R], t2v[SAL_R];

    #pragma unroll
    for (int r = 0; r < SAL_R; ++r) {
        const float4 tin = make_float4(ti4[r].x * tm4[r].x, ti4[r].y * tm4[r].y,
                                       ti4[r].z * tm4[r].z, ti4[r].w * tm4[r].w);
        const int pb0 = min(max((int)(pmz[r].x * 2000.0f), 0), SAL_NUM_BINS - 1);
        const int pb1 = min(max((int)(pmz[r].y * 2000.0f), 0), SAL_NUM_BINS - 1);
        const int pb2 = min(max((int)(pmz[r].z * 2000.0f), 0), SAL_NUM_BINS - 1);
        const int pb3 = min(max((int)(pmz[r].w * 2000.0f), 0), SAL_NUM_BINS - 1);
        const int tb0 = min(max((int)(tmz[r].x * 2000.0f), 0), SAL_NUM_BINS - 1);
        const int tb1 = min(max((int)(tmz[r].y * 2000.0f), 0), SAL_NUM_BINS - 1);
        const int tb2 = min(max((int)(tmz[r].z * 2000.0f), 0), SAL_NUM_BINS - 1);
        const int tb3 = min(max((int)(tmz[r].w * 2000.0f), 0), SAL_NUM_BINS - 1);

        // ---- phase Q: target histogram ----
        atomicAdd(&hist[tb0], tin.x);      // ds_add_f32, wave-private
        atomicAdd(&hist[tb1], tin.y);
        atomicAdd(&hist[tb2], tin.z);
        atomicAdd(&hist[tb3], tin.w);

        float dot = 0.f, p2 = 0.f, t2 = 0.f;
        dot = fmaf(pin[r].x, hist[pb0], dot);   // q at pred bins (0 if untouched)
        dot = fmaf(pin[r].y, hist[pb1], dot);
        dot = fmaf(pin[r].z, hist[pb2], dot);
        dot = fmaf(pin[r].w, hist[pb3], dot);
        t2  = fmaf(tin.x, hist[tb0], t2);
        t2  = fmaf(tin.y, hist[tb1], t2);
        t2  = fmaf(tin.z, hist[tb2], t2);
        t2  = fmaf(tin.w, hist[tb3], t2);

        // undo Q (in-order DS: the reads above complete first)
        hist[tb0] = 0.0f; hist[tb1] = 0.0f; hist[tb2] = 0.0f; hist[tb3] = 0.0f;

        // ---- phase P: pred histogram ----
        atomicAdd(&hist[pb0], pin[r].x);
        atomicAdd(&hist[pb1], pin[r].y);
        atomicAdd(&hist[pb2], pin[r].z);
        atomicAdd(&hist[pb3], pin[r].w);

        p2 = fmaf(pin[r].x, hist[pb0], p2);
        p2 = fmaf(pin[r].y, hist[pb1], p2);
        p2 = fmaf(pin[r].z, hist[pb2], p2);
        p2 = fmaf(pin[r].w, hist[pb3], p2);

        if (r < SAL_R - 1) {               // undo P (not needed on last row)
            hist[pb0] = 0.0f; hist[pb1] = 0.0f; hist[pb2] = 0.0f; hist[pb3] = 0.0f;
        }

        dotv[r] = dot; p2v[r] = p2; t2v[r] = t2;
    }

    // batched reduces: 6 independent chains hide the cross-lane latency.
    // Same __shfl_down butterfly as v1 -> bit-identical lane-0 sums.
    #pragma unroll
    for (int off = 32; off > 0; off >>= 1) {
        #pragma unroll
        for (int r = 0; r < SAL_R; ++r) {
            dotv[r] += __shfl_down(dotv[r], off, 64);
            p2v[r]  += __shfl_down(p2v[r],  off, 64);
            t2v[r]  += __shfl_down(t2v[r],  off, 64);
        }
    }

    if (l == 0) {
        float s = 0.f;
        #pragma unroll
        for (int r = 0; r < SAL_R; ++r) {
            const float pn = fmaxf(sqrtf(p2v[r]), 1e-8f);
            const float tn = fmaxf(sqrtf(t2v[r]), 1e-8f);
            float cs = dotv[r] / (pn * tn);
            cs = fminf(fmaxf(cs, -1.0f), 1.0f);
            s += acosf(cs) * (float)(1.0 / M_PI);
        }
        block_partial[blockIdx.x] = s;     // partial[i] = ang(2i)+ang(2i+1), same as v1
    }
}

__global__ __launch_bounds__(256) void sal_reduce_kernel(
    const float* __restrict__ wave_partial, float* __restrict__ out)
{
    const int t = threadIdx.x;
    const float4* wp4 = (const float4*)wave_partial;
    float s = 0.0f;
    #pragma unroll
    for (int i = 0; i < SAL_GRID / 4 / 256; ++i) {   // 1024 float4
        float4 v = wp4[t + i * 256];
        s += (v.x + v.y) + (v.z + v.w);
    }
    #pragma unroll
    for (int off = 32; off > 0; off >>= 1) s += __shfl_down(s, off, 64);
    __shared__ float rbuf[4];
    if ((t & 63) == 0) rbuf[t >> 6] = s;
    __syncthreads();
    if (t == 0) out[0] = ((rbuf[0] + rbuf[1]) + (rbuf[2] + rbuf[3])) * (float)(1.0 / SAL_B);
}

extern "C" void kernel_launch(void* const* d_in, const int* in_sizes, int n_in,
                              void* d_out, int out_size, void* d_ws, size_t ws_size,
                              hipStream_t stream) {
    const float* pred_mz   = (const float*)d_in[0];
    const float* pred_int  = (const float*)d_in[1];
    const float* targ_mz   = (const float*)d_in[2];
    const float* targ_int  = (const float*)d_in[3];
    const float* targ_mask = (const float*)d_in[4];
    float* block_partial = (float*)d_ws;   // 4096 floats, fully overwritten
    float* out = (float*)d_out;

    sal_row_kernel<<<SAL_GRID, 64, 0, stream>>>(pred_mz, pred_int, targ_mz,
                                                targ_int, targ_mask, block_partial);
    sal_reduce_kernel<<<1, 256, 0, stream>>>(block_partial, out);
}

// Round 2
// 106.486 us; speedup vs baseline: 1.0058x; 1.0058x over previous
//
#include <hip/hip_runtime.h>
#include <math.h>

// SpectralAngleLoss: B=8192 rows, N=256 peaks, 2000 bins.
//
// Identity: with p[b] the final histogram, dot = sum_i pin_i*q[pbin_i],
// p2 = sum_i pin_i*p[pbin_i], t2 = sum_j tin_j*q[tbin_j] -> scalar LDS
// reads per peak after the scatter; no 2000-bin scan.
//
// v3: v1's block shape (256 thr = 4 waves, grid 1024 -> fewer WGs than
// v2's 4096 single-wave WGs) + v2's single 8 KB hist per wave with TWO
// PHASES per row (target scatter/gather/undo, then pred). 32 KB LDS/block
// -> 4 resident blocks/CU (LDS would allow 5) = 16 waves/CU. All DS ops
// wave-ordered (wave-private hist + in-order DS pipe) -> zero
// __syncthreads, fully deterministic, bit-identical math to v2 (absmax 0).

#define SAL_NUM_BINS 2000
#define SAL_B 8192
#define SAL_N 256

__global__ __launch_bounds__(256, 4) void sal_row_kernel(
    const float* __restrict__ pred_mz,
    const float* __restrict__ pred_int,
    const float* __restrict__ targ_mz,
    const float* __restrict__ targ_int,
    const float* __restrict__ targ_mask,
    float* __restrict__ wave_partial)     // 4096 entries: sum of 2 angles
{
    __shared__ __align__(16) float hist[4][SAL_NUM_BINS];   // 32000 B
    const int t = threadIdx.x;
    const int w = t >> 6;                 // wave in block
    const int l = t & 63;                 // lane
    const int rowA  = blockIdx.x * 8 + w * 2;    // two consecutive rows/wave
    const int baseA = rowA * SAL_N;

    // issue both rows' global loads first (10 x 16B/lane, coalesced)
    float4 pmz[2], pin[2], tmz[2], ti4[2], tm4[2];
    #pragma unroll
    for (int r = 0; r < 2; ++r) {
        const int base = baseA + r * SAL_N;
        pmz[r] = ((const float4*)(pred_mz   + base))[l];
        pin[r] = ((const float4*)(pred_int  + base))[l];
        tmz[r] = ((const float4*)(targ_mz   + base))[l];
        ti4[r] = ((const float4*)(targ_int  + base))[l];
        tm4[r] = ((const float4*)(targ_mask + base))[l];
    }

    // zero this wave's private 8 KB under the loads (500 float4 / 64 lanes).
    // Single wave owns the region -> in-order DS, no barrier needed.
    {
        float4* h4 = (float4*)&hist[w][0];
        const float4 z = make_float4(0.f, 0.f, 0.f, 0.f);
        #pragma unroll
        for (int i = 0; i < 8; ++i) {
            const int idx = l + i * 64;
            if (idx < SAL_NUM_BINS / 4) h4[idx] = z;
        }
    }

    float* __restrict__ h = &hist[w][0];
    float dotv[2], p2v[2], t2v[2];

    #pragma unroll
    for (int r = 0; r < 2; ++r) {
        const float4 tin = make_float4(ti4[r].x * tm4[r].x, ti4[r].y * tm4[r].y,
                                       ti4[r].z * tm4[r].z, ti4[r].w * tm4[r].w);
        const int pb0 = min(max((int)(pmz[r].x * 2000.0f), 0), SAL_NUM_BINS - 1);
        const int pb1 = min(max((int)(pmz[r].y * 2000.0f), 0), SAL_NUM_BINS - 1);
        const int pb2 = min(max((int)(pmz[r].z * 2000.0f), 0), SAL_NUM_BINS - 1);
        const int pb3 = min(max((int)(pmz[r].w * 2000.0f), 0), SAL_NUM_BINS - 1);
        const int tb0 = min(max((int)(tmz[r].x * 2000.0f), 0), SAL_NUM_BINS - 1);
        const int tb1 = min(max((int)(tmz[r].y * 2000.0f), 0), SAL_NUM_BINS - 1);
        const int tb2 = min(max((int)(tmz[r].z * 2000.0f), 0), SAL_NUM_BINS - 1);
        const int tb3 = min(max((int)(tmz[r].w * 2000.0f), 0), SAL_NUM_BINS - 1);

        // ---- phase Q: target histogram ----
        atomicAdd(&h[tb0], tin.x);         // ds_add_f32, wave-private
        atomicAdd(&h[tb1], tin.y);
        atomicAdd(&h[tb2], tin.z);
        atomicAdd(&h[tb3], tin.w);

        float dot = 0.f, p2 = 0.f, t2 = 0.f;
        dot = fmaf(pin[r].x, h[pb0], dot);   // q at pred bins (0 if untouched)
        dot = fmaf(pin[r].y, h[pb1], dot);
        dot = fmaf(pin[r].z, h[pb2], dot);
        dot = fmaf(pin[r].w, h[pb3], dot);
        t2  = fmaf(tin.x, h[tb0], t2);
        t2  = fmaf(tin.y, h[tb1], t2);
        t2  = fmaf(tin.z, h[tb2], t2);
        t2  = fmaf(tin.w, h[tb3], t2);

        // undo Q (in-order DS: the reads above complete first)
        h[tb0] = 0.0f; h[tb1] = 0.0f; h[tb2] = 0.0f; h[tb3] = 0.0f;

        // ---- phase P: pred histogram ----
        atomicAdd(&h[pb0], pin[r].x);
        atomicAdd(&h[pb1], pin[r].y);
        atomicAdd(&h[pb2], pin[r].z);
        atomicAdd(&h[pb3], pin[r].w);

        p2 = fmaf(pin[r].x, h[pb0], p2);
        p2 = fmaf(pin[r].y, h[pb1], p2);
        p2 = fmaf(pin[r].z, h[pb2], p2);
        p2 = fmaf(pin[r].w, h[pb3], p2);

        if (r < 1) {                        // undo P (not needed on last row)
            h[pb0] = 0.0f; h[pb1] = 0.0f; h[pb2] = 0.0f; h[pb3] = 0.0f;
        }

        dotv[r] = dot; p2v[r] = p2; t2v[r] = t2;
    }

    // batched reduces: 6 independent chains hide cross-lane latency.
    // Same __shfl_down butterfly as v1/v2 -> bit-identical lane-0 sums.
    #pragma unroll
    for (int off = 32; off > 0; off >>= 1) {
        #pragma unroll
        for (int r = 0; r < 2; ++r) {
            dotv[r] += __shfl_down(dotv[r], off, 64);
            p2v[r]  += __shfl_down(p2v[r],  off, 64);
            t2v[r]  += __shfl_down(t2v[r],  off, 64);
        }
    }

    if (l == 0) {
        float s = 0.f;
        #pragma unroll
        for (int r = 0; r < 2; ++r) {
            const float pn = fmaxf(sqrtf(p2v[r]), 1e-8f);
            const float tn = fmaxf(sqrtf(t2v[r]), 1e-8f);
            float cs = dotv[r] / (pn * tn);
            cs = fminf(fmaxf(cs, -1.0f), 1.0f);
            s += acosf(cs) * (float)(1.0 / M_PI);
        }
        wave_partial[blockIdx.x * 4 + w] = s;   // same layout as v1
    }
}

__global__ __launch_bounds__(256) void sal_reduce_kernel(
    const float* __restrict__ wave_partial, float* __restrict__ out)
{
    const int t = threadIdx.x;
    const float4* wp4 = (const float4*)wave_partial;
    float s = 0.0f;
    #pragma unroll
    for (int i = 0; i < 4096 / 4 / 256; ++i) {   // 1024 float4
        float4 v = wp4[t + i * 256];
        s += (v.x + v.y) + (v.z + v.w);
    }
    #pragma unroll
    for (int off = 32; off > 0; off >>= 1) s += __shfl_down(s, off, 64);
    __shared__ float rbuf[4];
    if ((t & 63) == 0) rbuf[t >> 6] = s;
    __syncthreads();
    if (t == 0) out[0] = ((rbuf[0] + rbuf[1]) + (rbuf[2] + rbuf[3])) * (float)(1.0 / SAL_B);
}

extern "C" void kernel_launch(void* const* d_in, const int* in_sizes, int n_in,
                              void* d_out, int out_size, void* d_ws, size_t ws_size,
                              hipStream_t stream) {
    const float* pred_mz   = (const float*)d_in[0];
    const float* pred_int  = (const float*)d_in[1];
    const float* targ_mz   = (const float*)d_in[2];
    const float* targ_int  = (const float*)d_in[3];
    const float* targ_mask = (const float*)d_in[4];
    float* wave_partial = (float*)d_ws;   // 4096 floats, fully overwritten
    float* out = (float*)d_out;

    sal_row_kernel<<<SAL_B / 8, 256, 0, stream>>>(pred_mz, pred_int, targ_mz,
                                                  targ_int, targ_mask, wave_partial);
    sal_reduce_kernel<<<1, 256, 0, stream>>>(wave_partial, out);
}